// Round 1
// baseline (48928.909 us; speedup 1.0000x reference)
//
#include <hip/hip_runtime.h>

// GRU: B=64, T=512, D=128, H=512. All fp32.
// Kernels: init_ws (zero barrier counters) -> xproj (input projections, written
// into output regions as scratch) -> gru_scan (persistent 256-WG scan with
// per-rowgroup spin barriers) -> ys_k (output head).

#define BB 64
#define TT 512
#define DD 128
#define HH 512

static constexpr size_t NBT  = (size_t)BB * TT;      // 32768
static constexpr size_t NBTH = NBT * HH;             // 16777216
static constexpr size_t OUT_YS = 0;
static constexpr size_t OUT_HS = NBT;                 // holds xh before step t, h after
static constexpr size_t OUT_ZS = NBT + 1 * NBTH;      // holds xr before step t, z after
static constexpr size_t OUT_RS = NBT + 2 * NBTH;
static constexpr size_t OUT_LK = NBT + 3 * NBTH;
static constexpr size_t OUT_RD = NBT + 4 * NBTH;      // holds xz before step t, rdiag after

// ---------------------------------------------------------------- init ------
__global__ void init_ws(unsigned int* __restrict__ ctrs) {
  ctrs[threadIdx.x] = 0u;  // 512 dwords = 2048 B covers all 8 counters (256B stride)
}

// ---------------------------------------------------------------- xproj -----
// out[m][j] = sum_k x[m][k] * W[j][k] + Wb[j], m = b*T+t.
// mat 0 (Wz) -> OUT_RD region, mat 1 (Wr) -> OUT_ZS, mat 2 (Wh) -> OUT_HS.
// Tiles: BM=64, BN=32, K=128 (full). 128 threads, 4x4 micro-tile.
__global__ __launch_bounds__(128) void xproj(
    const float* __restrict__ x,
    const float* __restrict__ Wz, const float* __restrict__ Wzb,
    const float* __restrict__ Wr, const float* __restrict__ Wrb,
    const float* __restrict__ Wh, const float* __restrict__ Whb,
    float* __restrict__ dout)
{
  const int gid = blockIdx.x;
  const int mt  = gid & 511;        // 512 M tiles
  const int nt  = (gid >> 9) & 15;  // 16 N tiles
  const int mat = gid >> 13;        // 0..2
  const float* W; const float* Wb; size_t ob;
  if (mat == 0)      { W = Wz; Wb = Wzb; ob = OUT_RD; }
  else if (mat == 1) { W = Wr; Wb = Wrb; ob = OUT_ZS; }
  else               { W = Wh; Wb = Whb; ob = OUT_HS; }
  const int m0 = mt * 64, jb = nt * 32;
  __shared__ float A_l[64][132];
  __shared__ float W_l[32][132];
  const int tid = threadIdx.x;
#pragma unroll
  for (int it = 0; it < 16; ++it) {
    int f = it * 512 + tid * 4;
    int r = f >> 7, kk = f & 127;
    *(float4*)&A_l[r][kk] = *(const float4*)&x[(size_t)(m0 + r) * DD + kk];
  }
#pragma unroll
  for (int it = 0; it < 8; ++it) {
    int f = it * 512 + tid * 4;
    int r = f >> 7, kk = f & 127;
    *(float4*)&W_l[r][kk] = *(const float4*)&W[(size_t)(jb + r) * DD + kk];
  }
  __syncthreads();
  const int ty = tid >> 3, tx = tid & 7;  // 16 x 8
  float acc[4][4] = {};
  for (int k4 = 0; k4 < 128; k4 += 4) {
    float4 av[4], wv[4];
#pragma unroll
    for (int i = 0; i < 4; ++i) av[i] = *(const float4*)&A_l[ty * 4 + i][k4];
#pragma unroll
    for (int j = 0; j < 4; ++j) wv[j] = *(const float4*)&W_l[tx * 4 + j][k4];
#pragma unroll
    for (int i = 0; i < 4; ++i)
#pragma unroll
      for (int j = 0; j < 4; ++j) {
        acc[i][j] = fmaf(av[i].x, wv[j].x, acc[i][j]);
        acc[i][j] = fmaf(av[i].y, wv[j].y, acc[i][j]);
        acc[i][j] = fmaf(av[i].z, wv[j].z, acc[i][j]);
        acc[i][j] = fmaf(av[i].w, wv[j].w, acc[i][j]);
      }
  }
#pragma unroll
  for (int j = 0; j < 4; ++j) {
    const int jj = jb + tx * 4 + j;
    const float bv = Wb[jj];
#pragma unroll
    for (int i = 0; i < 4; ++i) {
      const int mm = m0 + ty * 4 + i;
      dout[ob + (size_t)mm * HH + jj] = acc[i][j] + bv;
    }
  }
}

// ---------------------------------------------------------------- scan ------
// 256 WGs = 8 rowgroups (8 batch rows) x 32 column slices (16 cols).
// U slices live in registers (48 VGPR/lane). h / r*h exchanged via global
// memory with per-rowgroup monotonic-counter spin barriers (2 per step).
__device__ __forceinline__ void rg_barrier(unsigned int* ctr, unsigned int target) {
  __syncthreads();
  if (threadIdx.x == 0) {
    __threadfence();  // release prior global writes (device scope)
    __hip_atomic_fetch_add(ctr, 1u, __ATOMIC_ACQ_REL, __HIP_MEMORY_SCOPE_AGENT);
    unsigned int v;
    do {
      v = __hip_atomic_load(ctr, __ATOMIC_ACQUIRE, __HIP_MEMORY_SCOPE_AGENT);
      if (v < target) __builtin_amdgcn_s_sleep(1);
    } while (v < target);
  }
  __syncthreads();
  __threadfence();    // acquire side: every thread invalidates before reading peers' data
}

__global__ __launch_bounds__(512) void gru_scan(
    const float* __restrict__ Uz, const float* __restrict__ Ur,
    const float* __restrict__ Uh, float* __restrict__ dout,
    float* __restrict__ rhbuf, unsigned int* __restrict__ ctrs)
{
  const int tid  = threadIdx.x;
  const int bid  = blockIdx.x;
  const int rg   = bid >> 5;        // rowgroup 0..7
  const int cs   = bid & 31;        // column slice 0..31
  const int b0   = rg * 8;
  const int j0   = cs * 16;
  const int w    = tid >> 6;        // wave 0..7 -> k octant
  const int lane = tid & 63;
  const int col  = lane & 15;       // local column 0..15
  const int kblk = lane >> 4;       // k sub-block 0..3
  const int kbase = w * 64 + kblk * 16;

  __shared__ float ht_l[512][9];    // h_prev, [k][row], stride 9 to spread banks
  __shared__ float rt_l[512][9];    // r*h_prev
  __shared__ float part_l[2 * 8 * 16 * 9];  // per-wave partial sums
  __shared__ float zl[8][17], rl[8][17];
  __shared__ float dz_l[16], dr_l[16], dh_l[16];

  // U fragments -> registers (one-time, 48 regs)
  float uzr[16], urr[16], uhr[16];
  {
    const size_t ub = (size_t)(j0 + col) * HH + kbase;
#pragma unroll
    for (int q = 0; q < 4; ++q) {
      float4 a = *(const float4*)(Uz + ub + q * 4);
      float4 b = *(const float4*)(Ur + ub + q * 4);
      float4 c = *(const float4*)(Uh + ub + q * 4);
      uzr[q * 4 + 0] = a.x; uzr[q * 4 + 1] = a.y; uzr[q * 4 + 2] = a.z; uzr[q * 4 + 3] = a.w;
      urr[q * 4 + 0] = b.x; urr[q * 4 + 1] = b.y; urr[q * 4 + 2] = b.z; urr[q * 4 + 3] = b.w;
      uhr[q * 4 + 0] = c.x; uhr[q * 4 + 1] = c.y; uhr[q * 4 + 2] = c.z; uhr[q * 4 + 3] = c.w;
    }
  }
  if (tid < 16) {
    const int j = j0 + tid;
    dz_l[tid] = Uz[(size_t)j * HH + j];
    dr_l[tid] = Ur[(size_t)j * HH + j];
    dh_l[tid] = Uh[(size_t)j * HH + j];
  }

  float* __restrict__ hs_o = dout + OUT_HS;
  float* __restrict__ zs_o = dout + OUT_ZS;
  float* __restrict__ rs_o = dout + OUT_RS;
  float* __restrict__ lk_o = dout + OUT_LK;
  float* __restrict__ rd_o = dout + OUT_RD;
  unsigned int* ctr = ctrs + (size_t)rg * 64;  // 256 B stride per rowgroup

  const int om   = tid >> 7;        // 0: z(+g) owner, 1: r owner (tid<256)
  const int orow = (tid >> 4) & 7;
  const int ocol = tid & 15;
  const int srow = tid >> 6;        // staging: row
  const int sjb  = (tid & 63) * 8;  // staging: 8 consecutive cols

#pragma unroll 1
  for (int t = 0; t < TT; ++t) {
    const size_t xbase = ((size_t)(b0 + orow) * TT + t) * HH + (j0 + ocol);
    // prefetch x-projection inputs (xz from RD region, xr from ZS region)
    float xin = 0.f;
    if (tid < 256) xin = (om == 0) ? rd_o[xbase] : zs_o[xbase];

    // ---- stage h_prev into ht_l ----
    if (t == 0) {
#pragma unroll
      for (int i2 = 0; i2 < 8; ++i2) ht_l[sjb + i2][srow] = 0.f;
    } else {
      const float* hp = hs_o + ((size_t)(b0 + srow) * TT + (t - 1)) * HH + sjb;
      float4 v0 = *(const float4*)(hp);
      float4 v1 = *(const float4*)(hp + 4);
      ht_l[sjb + 0][srow] = v0.x; ht_l[sjb + 1][srow] = v0.y;
      ht_l[sjb + 2][srow] = v0.z; ht_l[sjb + 3][srow] = v0.w;
      ht_l[sjb + 4][srow] = v1.x; ht_l[sjb + 5][srow] = v1.y;
      ht_l[sjb + 6][srow] = v1.z; ht_l[sjb + 7][srow] = v1.w;
    }
    __syncthreads();

    // ---- phase A: az, ar partials ----
    float accz[8] = {0, 0, 0, 0, 0, 0, 0, 0};
    float accr[8] = {0, 0, 0, 0, 0, 0, 0, 0};
#pragma unroll
    for (int i = 0; i < 16; ++i) {
      const int k = kbase + i;
      const float uz = uzr[i], ur = urr[i];
#pragma unroll
      for (int r8 = 0; r8 < 8; ++r8) {
        const float hv = ht_l[k][r8];
        accz[r8] = fmaf(uz, hv, accz[r8]);
        accr[r8] = fmaf(ur, hv, accr[r8]);
      }
    }
#pragma unroll
    for (int r8 = 0; r8 < 8; ++r8) {
      accz[r8] += __shfl_xor(accz[r8], 16, 64);
      accz[r8] += __shfl_xor(accz[r8], 32, 64);
      accr[r8] += __shfl_xor(accr[r8], 16, 64);
      accr[r8] += __shfl_xor(accr[r8], 32, 64);
    }
    if (kblk == 0) {
#pragma unroll
      for (int r8 = 0; r8 < 8; ++r8) {
        part_l[((0 * 8 + r8) * 16 + col) * 9 + w] = accz[r8];
        part_l[((1 * 8 + r8) * 16 + col) * 9 + w] = accr[r8];
      }
    }
    __syncthreads();
    if (tid < 256) {
      const float* pp = &part_l[((om * 8 + orow) * 16 + ocol) * 9];
      const float s = ((pp[0] + pp[1]) + (pp[2] + pp[3])) + ((pp[4] + pp[5]) + (pp[6] + pp[7]));
      const float a = xin + s;
      const float v = 1.f / (1.f + __expf(-a));
      if (om == 0) {
        zl[orow][ocol] = v;
        zs_o[xbase] = v;           // overwrite xr slot only after all xr reads (pre-read + sync)
        lk_o[xbase] = 1.f - v;
      } else {
        rl[orow][ocol] = v;
        rs_o[xbase] = v;
        const float hj = ht_l[j0 + ocol][orow];
        rhbuf[(size_t)(b0 + orow) * HH + (j0 + ocol)] = v * hj;
      }
    }
    rg_barrier(ctr, 32u * (2 * t + 1));

    // ---- phase B: g, h, rdiag ----
    float xh = 0.f;
    if (tid < 128) xh = hs_o[xbase];  // xh lives in hs slot until we overwrite below
    {
      const float* rp = rhbuf + (size_t)(b0 + srow) * HH + sjb;
      float4 v0 = *(const float4*)(rp);
      float4 v1 = *(const float4*)(rp + 4);
      rt_l[sjb + 0][srow] = v0.x; rt_l[sjb + 1][srow] = v0.y;
      rt_l[sjb + 2][srow] = v0.z; rt_l[sjb + 3][srow] = v0.w;
      rt_l[sjb + 4][srow] = v1.x; rt_l[sjb + 5][srow] = v1.y;
      rt_l[sjb + 6][srow] = v1.z; rt_l[sjb + 7][srow] = v1.w;
    }
    __syncthreads();

    float acch[8] = {0, 0, 0, 0, 0, 0, 0, 0};
#pragma unroll
    for (int i = 0; i < 16; ++i) {
      const int k = kbase + i;
      const float uh = uhr[i];
#pragma unroll
      for (int r8 = 0; r8 < 8; ++r8) {
        acch[r8] = fmaf(uh, rt_l[k][r8], acch[r8]);
      }
    }
#pragma unroll
    for (int r8 = 0; r8 < 8; ++r8) {
      acch[r8] += __shfl_xor(acch[r8], 16, 64);
      acch[r8] += __shfl_xor(acch[r8], 32, 64);
    }
    if (kblk == 0) {
#pragma unroll
      for (int r8 = 0; r8 < 8; ++r8) {
        part_l[(r8 * 16 + col) * 9 + w] = acch[r8];
      }
    }
    __syncthreads();
    if (tid < 128) {
      const float* pp = &part_l[(orow * 16 + ocol) * 9];
      const float s = ((pp[0] + pp[1]) + (pp[2] + pp[3])) + ((pp[4] + pp[5]) + (pp[6] + pp[7]));
      const float g = tanhf(xh + s);
      const float z = zl[orow][ocol];
      const float r = rl[orow][ocol];
      const float hj = ht_l[j0 + ocol][orow];
      const float hn = (1.f - z) * hj + z * g;
      hs_o[xbase] = hn;
      const float zp  = z * (1.f - z);
      const float rp2 = r * (1.f - r);
      const float gp  = 1.f - g * g;
      rd_o[xbase] = (g - hj) * zp * dz_l[ocol] + z * gp * dh_l[ocol] * (r + hj * rp2 * dr_l[ocol]);
    }
    rg_barrier(ctr, 32u * (2 * t + 2));
  }
}

// ---------------------------------------------------------------- ys --------
__global__ __launch_bounds__(256) void ys_k(
    const float* __restrict__ hs, const float* __restrict__ ow,
    const float* __restrict__ obv, float* __restrict__ ys)
{
  const int m = blockIdx.x * 4 + (threadIdx.x >> 6);
  const int lane = threadIdx.x & 63;
  const float* hrow = hs + (size_t)m * HH + lane * 8;
  const float* wrow = ow + lane * 8;
  float4 h0 = *(const float4*)hrow;
  float4 h1 = *(const float4*)(hrow + 4);
  float4 w0 = *(const float4*)wrow;
  float4 w1 = *(const float4*)(wrow + 4);
  float s = h0.x * w0.x + h0.y * w0.y + h0.z * w0.z + h0.w * w0.w
          + h1.x * w1.x + h1.y * w1.y + h1.z * w1.z + h1.w * w1.w;
#pragma unroll
  for (int m2 = 1; m2 < 64; m2 <<= 1) s += __shfl_xor(s, m2, 64);
  if (lane == 0) ys[m] = s + obv[0];
}

// ---------------------------------------------------------------- launch ----
extern "C" void kernel_launch(void* const* d_in, const int* in_sizes, int n_in,
                              void* d_out, int out_size, void* d_ws, size_t ws_size,
                              hipStream_t stream) {
  (void)in_sizes; (void)n_in; (void)out_size; (void)ws_size;
  const float* x   = (const float*)d_in[0];
  const float* Wz  = (const float*)d_in[1];
  const float* Wzb = (const float*)d_in[2];
  const float* Wr  = (const float*)d_in[3];
  const float* Wrb = (const float*)d_in[4];
  const float* Wh  = (const float*)d_in[5];
  const float* Whb = (const float*)d_in[6];
  const float* Uz  = (const float*)d_in[7];
  const float* Ur  = (const float*)d_in[8];
  const float* Uh  = (const float*)d_in[9];
  const float* ow  = (const float*)d_in[10];
  const float* obv = (const float*)d_in[11];
  float* out = (float*)d_out;
  unsigned int* ctrs = (unsigned int*)d_ws;                 // 2048 B counters
  float* rhb = (float*)((char*)d_ws + 4096);                // 64*512 fp32 r*h buffer

  init_ws<<<1, 512, 0, stream>>>(ctrs);
  xproj<<<24576, 128, 0, stream>>>(x, Wz, Wzb, Wr, Wrb, Wh, Whb, out);
  // 256 WGs: capacity >= 2 WGs/CU (47 KB LDS, 512 thr) so all are co-resident
  // under any packing -> spin barriers cannot deadlock.
  gru_scan<<<256, 512, 0, stream>>>(Uz, Ur, Uh, out, rhb, ctrs);
  ys_k<<<8192, 256, 0, stream>>>(out + OUT_HS, ow, obv, out + OUT_YS);
}